// Round 14
// baseline (562.325 us; speedup 1.0000x reference)
//
#include <hip/hip_runtime.h>
#include <math.h>

#define NN 50000
#define EE 800000
#define DD 32

typedef float v2f __attribute__((ext_vector_type(2)));

// deg packing: one double atomic per edge carries both count and sum(w):
//   pack += 65536.0 + w   ->  count = floor(pack/65536), sumw = pack - 65536*count
__device__ __forceinline__ int pack_count(double p){ return (int)(p * (1.0/65536.0)); }
__device__ __forceinline__ float pack_sumw(double p){ return (float)(p - 65536.0 * (double)pack_count(p)); }

// ---------------- setup kernels ----------------

__global__ __launch_bounds__(256) void k_zero(float* p, int count){
  int i = blockIdx.x*256 + threadIdx.x;
  if (i < count) p[i] = 0.f;
}

__global__ __launch_bounds__(256) void k_hist(const int* __restrict__ node_out,
                                              const float* __restrict__ ew,
                                              double* __restrict__ deg_pack){
  int e = blockIdx.x*256 + threadIdx.x;
  if (e < EE){
    int o = node_out[e];
    atomicAdd(&deg_pack[o], 65536.0 + (double)ew[e]);
  }
}

// fused: per-block count partial (for scan) + global logsum atomic
__global__ __launch_bounds__(256) void k_stats1(const double* __restrict__ deg_pack,
                                                int* __restrict__ partials,
                                                float* __restrict__ logsum){
  __shared__ int sd[256];
  __shared__ float sf[256];
  int t = threadIdx.x; int n = blockIdx.x*256 + t;
  int cv = 0; float lv = 0.f;
  if (n < NN){
    double p = deg_pack[n];
    cv = pack_count(p);
    lv = logf(pack_sumw(p) + 1.f);
  }
  sd[t] = cv; sf[t] = lv; __syncthreads();
  for (int off = 128; off > 0; off >>= 1){
    if (t < off){ sd[t] += sd[t+off]; sf[t] += sf[t+off]; }
    __syncthreads();
  }
  if (t == 0){ partials[blockIdx.x] = sd[0]; atomicAdd(logsum, sf[0]); }
}

__global__ __launch_bounds__(256) void k_scan2(int* __restrict__ partials, int nb,
                                               int* __restrict__ row_start,
                                               int2* __restrict__ csr){
  __shared__ int sd[256];
  int t = threadIdx.x;
  int v = (t < nb) ? partials[t] : 0;
  sd[t] = v; __syncthreads();
  for (int off = 1; off < 256; off <<= 1){
    int x = (t >= off) ? sd[t-off] : 0;
    __syncthreads();
    sd[t] += x;
    __syncthreads();
  }
  if (t < nb) partials[t] = sd[t] - v;   // exclusive
  if (t == 0) row_start[NN] = EE;
  if (t < 32) csr[EE + t] = make_int2(0, 0);   // zero the pad tail (re-poisoned each call)
}

// fused: scan3 (row_start/cursor) + scales (logsum is final: stream-ordered)
__global__ __launch_bounds__(256) void k_scan3s(const double* __restrict__ deg_pack,
                                                const int* __restrict__ partials,
                                                const float* __restrict__ logsum,
                                                int* __restrict__ row_start,
                                                int* __restrict__ cursor,
                                                float* __restrict__ scale_arr,
                                                float* __restrict__ inv_arr){
  __shared__ int sd[256];
  int t = threadIdx.x; int n = blockIdx.x*256 + t;
  double p = (n < NN) ? deg_pack[n] : 0.0;
  int v = (n < NN) ? pack_count(p) : 0;
  sd[t] = v; __syncthreads();
  for (int off = 1; off < 256; off <<= 1){
    int x = (t >= off) ? sd[t-off] : 0;
    __syncthreads();
    sd[t] += x;
    __syncthreads();
  }
  if (n < NN){
    int rs = partials[blockIdx.x] + sd[t] - v;  // exclusive
    row_start[n] = rs; cursor[n] = rs;
    float mean = *logsum / (float)NN;
    float s = logf(pack_sumw(p) + 1.f) / mean;
    scale_arr[n] = s;
    inv_arr[n]   = 1.f / fmaxf(s, 0.01f);
  }
}

__global__ __launch_bounds__(256) void k_fillcsr(const int* __restrict__ node_in,
                                                 const int* __restrict__ node_out,
                                                 const float* __restrict__ ew,
                                                 int* __restrict__ cursor,
                                                 int2* __restrict__ csr){
  int e = blockIdx.x*256 + threadIdx.x;
  if (e < EE){
    int o = node_out[e];
    int pos = atomicAdd(&cursor[o], 1);
    int2 v; v.x = node_in[e]; v.y = __float_as_int(ew[e]);
    csr[pos] = v;
  }
}

// rel_input per layer (6x32) and query-part of final MLP (64)
__global__ __launch_bounds__(256) void k_prep(const float* __restrict__ qw,
                                              const float* __restrict__ rel_W,
                                              const float* __restrict__ rel_b,
                                              const float* __restrict__ W1,
                                              const float* __restrict__ b1,
                                              float* __restrict__ rel6,
                                              float* __restrict__ qc){
  int t = threadIdx.x;
  if (t < 192){
    int l = t >> 5, j = t & 31;
    float s = rel_b[t];
    for (int d = 0; d < 32; ++d) s += qw[d] * rel_W[l*1024 + d*32 + j];
    rel6[t] = s;
  } else if (t < 256){
    int j = t - 192;
    float s = b1[j];
    for (int k = 0; k < 32; ++k) s += qw[k] * W1[(32+k)*64 + j];
    qc[j] = s;
  }
}

__global__ __launch_bounds__(256) void k_init_h(const int* __restrict__ hidx,
                                                float* __restrict__ h,
                                                float* __restrict__ hT){
  int i = blockIdx.x*256 + threadIdx.x;
  int hv = *hidx;
  if (i < NN*DD){
    h[i]  = ((i >> 5) == hv) ? 0.f : 100.f;   // row-major: n = i/32
    int n2 = i % NN;                           // transposed: n = i % N
    hT[i] = (n2 == hv) ? 0.f : 100.f;
  }
}

// t[n] = dot(h[n], rel_layer5) for msg_score
__global__ __launch_bounds__(256) void k_dot(const float* __restrict__ h,
                                             const float* __restrict__ rel6,
                                             float* __restrict__ tdot){
  int n0 = blockIdx.x*256 + threadIdx.x;
  int n = (n0 < NN) ? n0 : NN-1;
  const float* relr = rel6 + 5*32;
  float s = 0.f;
  #pragma unroll
  for (int d = 0; d < 32; ++d) s += h[n*32 + d] * relr[d];
  if (n0 < NN) tdot[n0] = s;
}

// ---------------- fused per-layer kernel ----------------
// Block = 64 nodes, 512 threads = 8 waves.
// R13 post-mortem: csr was pipelined but the h-gathers were issued and
// consumed in the same batch -> each 4-edge batch exposed ~400 cyc of L3
// latency (VALUBusy 34%). This round software-pipelines the h/tdot gathers
// ONE BATCH AHEAD: iteration i issues h for batch i+1 (csr already in regs)
// and csr for batch i+2, then accumulates batch i from registers loaded a
// full iteration earlier. Steady state has no load->use wait. Edge order per
// node strictly sequential (bit-identical; PRED tie semantics preserved).
// launch_bounds(512,4): allocator cap 128 VGPR (pipeline needs ~85; the
// bound caps the allocator, not achievable occupancy).
// Phase 2: packed fp32 (v_pk_fma_f32) j-split, wave-uniform W -> s_load.
template<bool PRED>
__global__ __launch_bounds__(512, 4) void k_layer(const float* __restrict__ h,
                                               const float* __restrict__ hT,
                                               const float* __restrict__ rel6,
                                               const int* __restrict__ row_start,
                                               const int2* __restrict__ csr,
                                               const int* __restrict__ hidx,
                                               const float* __restrict__ tdot,
                                               const float* __restrict__ lin_W,
                                               const float* __restrict__ lin_b,
                                               const float* __restrict__ scale_arr,
                                               const float* __restrict__ inv_arr,
                                               float* __restrict__ h_next,
                                               float* __restrict__ hT_next,
                                               float* __restrict__ pred_out,
                                               int l){
  __shared__ float sh[128*65];
  int tid = threadIdx.x;
  int base = blockIdx.x * 64;
  int hv0 = *hidx;

  // ---- phase 1: aggregation (one 8-lane group per node; 2-stage pipeline) ----
  {
    int nl   = tid >> 3;     // group = node index in block, 0..63
    int quad = tid & 7;      // dims quad*4..+3
    float4 r4 = ((const float4*)(rel6 + l*32))[quad];
    int n0 = base + nl;
    bool valid = n0 < NN;
    int n = valid ? n0 : NN-1;
    int s0 = row_start[n], s1 = row_start[n+1];
    int deg = s1 - s0;
    float S10=0.f,S11=0.f,S12=0.f,S13=0.f;
    float S20=0.f,S21=0.f,S22=0.f,S23=0.f;
    float M0=-INFINITY,M1=-INFINITY,M2=-INFINITY,M3=-INFINITY;
    float m0=INFINITY,m1=INFINITY,m2=INFINITY,m3=INFINITY;
    float best=-INFINITY; int bi=NN;

#define H4(C) (((const float4*)(h + (C).x*32))[quad])
#define ACC1(C, A, T) { \
    float w = __int_as_float(C.y); \
    float p0=w*A.x, p1=w*A.y, p2=w*A.z, p3=w*A.w; \
    S10+=p0; S11+=p1; S12+=p2; S13+=p3; \
    S20+=p0*A.x; S21+=p1*A.y; S22+=p2*A.z; S23+=p3*A.w; \
    M0=fmaxf(M0,p0); M1=fmaxf(M1,p1); M2=fmaxf(M2,p2); M3=fmaxf(M3,p3); \
    m0=fminf(m0,p0); m1=fminf(m1,p1); m2=fminf(m2,p2); m3=fminf(m3,p3); \
    if (PRED){ \
      float sv = w*T; \
      if (sv > best){ best = sv; bi = C.x; } \
      else if (sv == best && C.x < bi) bi = C.x; \
    } }

    int nb4 = deg >> 2;
    // prologue (pad covers csr[s0..s0+7] up to EE+31; (0,0) entries -> h[0])
    int2 cA = csr[s0],   cB = csr[s0+1], cC = csr[s0+2], cD = csr[s0+3];
    int2 pA = csr[s0+4], pB = csr[s0+5], pC = csr[s0+6], pD = csr[s0+7];
    float4 a = H4(cA), b = H4(cB), c4 = H4(cC), d4 = H4(cD);
    float tA=0.f,tB=0.f,tC=0.f,tD=0.f;
    if (PRED){ tA=tdot[cA.x]; tB=tdot[cB.x]; tC=tdot[cC.x]; tD=tdot[cD.x]; }
    int e = s0;
    for (int i = 0; i < nb4 - 1; ++i, e += 4){
      // issue h/tdot for batch i+1 (csr already resident in p regs)
      float4 na = H4(pA), nb2 = H4(pB), nc = H4(pC), nd = H4(pD);
      float uA=0.f,uB=0.f,uC=0.f,uD=0.f;
      if (PRED){ uA=tdot[pA.x]; uB=tdot[pB.x]; uC=tdot[pC.x]; uD=tdot[pD.x]; }
      // issue csr for batch i+2
      int2 qA = csr[e+8], qB = csr[e+9], qC = csr[e+10], qD = csr[e+11];
      // accumulate batch i (all operands loaded >= 1 iteration ago)
      ACC1(cA, a, tA) ACC1(cB, b, tB) ACC1(cC, c4, tC) ACC1(cD, d4, tD)
      cA=pA; cB=pB; cC=pC; cD=pD;
      pA=qA; pB=qB; pC=qC; pD=qD;
      a=na; b=nb2; c4=nc; d4=nd;
      if (PRED){ tA=uA; tB=uB; tC=uC; tD=uD; }
    }
    if (nb4 > 0){
      // last full batch (h loaded in prologue or previous iteration)
      ACC1(cA, a, tA) ACC1(cB, b, tB) ACC1(cC, c4, tC) ACC1(cD, d4, tD)
      e += 4;
      int rem = s1 - e;            // 0..3, csr in pA..pC
      if (rem > 0){
        float4 x = H4(pA); float tx=0.f; if (PRED) tx=tdot[pA.x];
        ACC1(pA, x, tx)
        if (rem > 1){
          float4 y = H4(pB); float ty=0.f; if (PRED) ty=tdot[pB.x];
          ACC1(pB, y, ty)
          if (rem > 2){
            float4 z = H4(pC); float tz=0.f; if (PRED) tz=tdot[pC.x];
            ACC1(pC, z, tz)
          }
        }
      }
    } else if (deg > 0){
      // deg 1..3: edges in cA..cC with h already loaded in prologue
      ACC1(cA, a, tA)
      if (deg > 1){
        ACC1(cB, b, tB)
        if (deg > 2){ ACC1(cC, c4, tC) }
      }
    }
#undef ACC1
#undef H4

    // finalize (no cross-lane reduction needed)
    float bnd = (n == hv0) ? 0.f : 100.f;
    float cntf = (float)(deg + 1);
#define FIN(cc, rc, S1c, S2c, Mc, mc) { \
    float mxv, mnv; \
    if (deg > 0){ \
      float em = (rc >= 0.f) ? rc*Mc : rc*mc; \
      float en = (rc >= 0.f) ? rc*mc : rc*Mc; \
      mxv = fmaxf(em, bnd); mnv = fminf(en, bnd); \
    } else { mxv = bnd; mnv = bnd; } \
    float meanv = (rc*S1c + bnd) / cntf; \
    float sq    = (rc*rc*S2c + bnd*bnd) / cntf; \
    float sdv   = sqrtf(fmaxf(sq - meanv*meanv, 1e-6f)); \
    int d = quad*4 + cc; \
    sh[(d*4+0)*65 + nl] = meanv; \
    sh[(d*4+1)*65 + nl] = mxv; \
    sh[(d*4+2)*65 + nl] = mnv; \
    sh[(d*4+3)*65 + nl] = sdv; }
    FIN(0, r4.x, S10, S20, M0, m0)
    FIN(1, r4.y, S11, S21, M1, m1)
    FIN(2, r4.z, S12, S22, M2, m2)
    FIN(3, r4.w, S13, S23, M3, m3)
#undef FIN
    if (PRED && valid && quad == 0){
      float ss = (n == hv0) ? 0.f : 3200.f;   // boundary self-loop row sum, w=1
      if (ss > best){ best = ss; bi = n; }
      else if (ss == best && n < bi) bi = n;
      pred_out[n] = (float)bi;
    }
  }
  __syncthreads();

  // ---- phase 2: linear (8 waves, wave w -> j0 = w*4; node = lane) ----
  // packed fp32: v2f arithmetic -> v_pk_fma_f32 (2 FLOPs/inst)
  {
    const float* Wl = lin_W + (size_t)l * 13312;   // 416*32
    int lane = tid & 63;
    int j0 = __builtin_amdgcn_readfirstlane((tid >> 6) * 4);  // 0,4,...,28
    int n0 = base + lane;
    int n = (n0 < NN) ? n0 : NN-1;
    float sc = scale_arr[n], iv = inv_arr[n];
    v2f a01, a23;
    a01[0] = lin_b[l*32 + j0 + 0]; a01[1] = lin_b[l*32 + j0 + 1];
    a23[0] = lin_b[l*32 + j0 + 2]; a23[1] = lin_b[l*32 + j0 + 3];

    for (int k = 0; k < 32; ++k){
      float xv = hT[k*NN + n];
      const v2f* wr2 = (const v2f*)(Wl + k*32 + j0);
      v2f xv2; xv2[0] = xv; xv2[1] = xv;
      a01 += xv2 * wr2[0];
      a23 += xv2 * wr2[1];
    }
    for (int kp = 0; kp < 128; ++kp){
      float f = sh[kp*65 + lane];
      int d = kp >> 2, c = kp & 3;
      const v2f* w2 = (const v2f*)(Wl + (32 + d*12 + c*3)*32 + j0);
      float f1 = f*sc, f2 = f*iv;
      v2f fv;  fv[0]=f;  fv[1]=f;
      v2f f1v; f1v[0]=f1; f1v[1]=f1;
      v2f f2v; f2v[0]=f2; f2v[1]=f2;
      // rows are 32 floats = 16 v2f apart
      a01 += fv*w2[0] + f1v*w2[16] + f2v*w2[32];
      a23 += fv*w2[1] + f1v*w2[17] + f2v*w2[33];
    }

    if (n0 < NN){
      float vs[4] = { a01[0], a01[1], a23[0], a23[1] };
      #pragma unroll
      for (int j = 0; j < 4; ++j){
        float v = fmaxf(vs[j], 0.f);
        h_next[n0*32 + j0 + j] = v;
        hT_next[(j0+j)*NN + n0] = v;
      }
    }
  }
}

// ---------------- final MLP ----------------
__global__ __launch_bounds__(256) void k_mlp(const float* __restrict__ hT,
                                             const float* __restrict__ qc,
                                             const float* __restrict__ W1,
                                             const float* __restrict__ W2,
                                             const float* __restrict__ b2,
                                             float* __restrict__ out_score){
  int n0 = blockIdx.x*256 + threadIdx.x;
  int n = (n0 < NN) ? n0 : NN-1;
  float acc[64];
  #pragma unroll
  for (int j = 0; j < 64; ++j) acc[j] = qc[j];
  for (int k = 0; k < 32; ++k){
    float xv = hT[k*NN + n];
    const float* wr = W1 + k*64;
    #pragma unroll
    for (int j = 0; j < 64; ++j) acc[j] += xv * wr[j];
  }
  float s = b2[0];
  #pragma unroll
  for (int j = 0; j < 64; ++j) s += fmaxf(acc[j], 0.f) * W2[j];
  if (n0 < NN) out_score[n0] = s;
}

// ---------------- host launch ----------------
extern "C" void kernel_launch(void* const* d_in, const int* in_sizes, int n_in,
                              void* d_out, int out_size, void* d_ws, size_t ws_size,
                              hipStream_t stream){
  const int*   node_in  = (const int*)d_in[0];
  const int*   node_out = (const int*)d_in[1];
  const float* ew       = (const float*)d_in[2];
  const int*   hidx     = (const int*)d_in[3];
  const float* qw       = (const float*)d_in[4];
  const float* rel_W    = (const float*)d_in[5];
  const float* rel_b    = (const float*)d_in[6];
  const float* lin_W    = (const float*)d_in[7];
  const float* lin_b    = (const float*)d_in[8];
  const float* W1       = (const float*)d_in[9];
  const float* b1       = (const float*)d_in[10];
  const float* W2       = (const float*)d_in[11];
  const float* b2       = (const float*)d_in[12];
  float* out_score = (float*)d_out;
  float* out_pred  = out_score + NN;

  char* w = (char*)d_ws;
  size_t off = 0;
  auto take = [&](size_t bytes)->char*{
    char* p = w + off;
    off = (off + bytes + 255) & ~(size_t)255;
    return p;
  };
  double* deg_pack = (double*)take((size_t)NN*8 + 64*4);
  float*  logsum   = (float*)(deg_pack + NN);
  int*   row_start = (int*)take((size_t)(NN+1)*4);
  int*   cursor    = (int*)take((size_t)NN*4);
  int*   partials  = (int*)take(256*4);
  float* rel6      = (float*)take(192*4);
  float* qc        = (float*)take(64*4);
  float* scale_arr = (float*)take((size_t)NN*4);
  float* inv_arr   = (float*)take((size_t)NN*4);
  float* tdot      = (float*)take((size_t)NN*4);
  int2*  csr       = (int2*)take((size_t)(EE+32)*8);
  float* h_a       = (float*)take((size_t)NN*32*4);
  float* hT_a      = (float*)take((size_t)NN*32*4);
  float* h_b       = (float*)take((size_t)NN*32*4);
  float* hT_b      = (float*)take((size_t)NN*32*4);

  int zc = 2*NN + 64;   // N doubles == 2N floats, + logsum block
  int nb = (NN + 255) / 256;   // 196
  int nlb = (NN + 63) / 64;    // 782
  k_zero   <<<(zc+255)/256, 256, 0, stream>>>((float*)deg_pack, zc);
  k_hist   <<<(EE+255)/256, 256, 0, stream>>>(node_out, ew, deg_pack);
  k_stats1 <<<nb, 256, 0, stream>>>(deg_pack, partials, logsum);
  k_scan2  <<<1, 256, 0, stream>>>(partials, nb, row_start, csr);
  k_scan3s <<<nb, 256, 0, stream>>>(deg_pack, partials, logsum, row_start,
                                    cursor, scale_arr, inv_arr);
  k_fillcsr<<<(EE+255)/256, 256, 0, stream>>>(node_in, node_out, ew, cursor, csr);
  k_prep   <<<1, 256, 0, stream>>>(qw, rel_W, rel_b, W1, b1, rel6, qc);
  k_init_h <<<(NN*DD+255)/256, 256, 0, stream>>>(hidx, h_a, hT_a);

  float* hc = h_a;  float* hTc = hT_a;
  float* hn = h_b;  float* hTn = hT_b;
  for (int l = 0; l < 6; ++l){
    if (l == 5){
      k_dot<<<nb, 256, 0, stream>>>(hc, rel6, tdot);
      k_layer<true><<<nlb, 512, 0, stream>>>(hc, hTc, rel6, row_start, csr,
                                             hidx, tdot, lin_W, lin_b,
                                             scale_arr, inv_arr, hn, hTn,
                                             out_pred, l);
    } else {
      k_layer<false><<<nlb, 512, 0, stream>>>(hc, hTc, rel6, row_start, csr,
                                              hidx, tdot, lin_W, lin_b,
                                              scale_arr, inv_arr, hn, hTn,
                                              out_pred, l);
    }
    float* t1 = hc;  hc = hn;  hn = t1;
    float* t2 = hTc; hTc = hTn; hTn = t2;
  }
  k_mlp<<<nb, 256, 0, stream>>>(hTc, qc, W1, W2, b2, out_score);
}

// Round 15
// 490.353 us; speedup vs baseline: 1.1468x; 1.1468x over previous
//
#include <hip/hip_runtime.h>
#include <math.h>

#define NN 50000
#define EE 800000
#define DD 32
#define BSTR 64   // bucket stride (max degree 12-sigma margin over Poisson(16))

typedef float v2f __attribute__((ext_vector_type(2)));

// ---------------- setup kernels ----------------

__global__ __launch_bounds__(256) void k_zero(float* p, int count){
  int i = blockIdx.x*256 + threadIdx.x;
  if (i < count) p[i] = 0.f;
}

// one-pass CSR build into fixed-stride buckets: no hist, no scan
__global__ __launch_bounds__(256) void k_fillcsr(const int* __restrict__ node_in,
                                                 const int* __restrict__ node_out,
                                                 const float* __restrict__ ew,
                                                 int* __restrict__ cursor,
                                                 int2* __restrict__ csr){
  int e = blockIdx.x*256 + threadIdx.x;
  if (e < EE){
    int o = node_out[e];
    int pos = atomicAdd(&cursor[o], 1);
    int2 v; v.x = node_in[e]; v.y = __float_as_int(ew[e]);
    csr[o*BSTR + pos] = v;
  }
}

// per-node sum(w) over its (contiguous) bucket row + global logsum reduce
__global__ __launch_bounds__(256) void k_sumw(const int2* __restrict__ csr,
                                              const int* __restrict__ cursor,
                                              float* __restrict__ deg_w,
                                              float* __restrict__ logsum){
  __shared__ float sf[256];
  int t = threadIdx.x; int n = blockIdx.x*256 + t;
  float s = 0.f;
  if (n < NN){
    int deg = cursor[n];
    const int2* row = csr + n*BSTR;
    for (int i = 0; i < deg; ++i) s += __int_as_float(row[i].y);
    deg_w[n] = s;
  }
  sf[t] = (n < NN) ? logf(s + 1.f) : 0.f;
  __syncthreads();
  for (int off = 128; off > 0; off >>= 1){
    if (t < off) sf[t] += sf[t+off];
    __syncthreads();
  }
  if (t == 0) atomicAdd(logsum, sf[0]);
}

__global__ __launch_bounds__(256) void k_scales(const float* __restrict__ deg_w,
                                                const float* __restrict__ logsum,
                                                float* __restrict__ scale_arr,
                                                float* __restrict__ inv_arr){
  int n = blockIdx.x*256 + threadIdx.x;
  if (n < NN){
    float mean = *logsum / (float)NN;
    float s = logf(deg_w[n] + 1.f) / mean;
    scale_arr[n] = s;
    inv_arr[n]   = 1.f / fmaxf(s, 0.01f);
  }
}

// rel_input per layer (6x32) and query-part of final MLP (64)
__global__ __launch_bounds__(256) void k_prep(const float* __restrict__ qw,
                                              const float* __restrict__ rel_W,
                                              const float* __restrict__ rel_b,
                                              const float* __restrict__ W1,
                                              const float* __restrict__ b1,
                                              float* __restrict__ rel6,
                                              float* __restrict__ qc){
  int t = threadIdx.x;
  if (t < 192){
    int l = t >> 5, j = t & 31;
    float s = rel_b[t];
    for (int d = 0; d < 32; ++d) s += qw[d] * rel_W[l*1024 + d*32 + j];
    rel6[t] = s;
  } else if (t < 256){
    int j = t - 192;
    float s = b1[j];
    for (int k = 0; k < 32; ++k) s += qw[k] * W1[(32+k)*64 + j];
    qc[j] = s;
  }
}

__global__ __launch_bounds__(256) void k_init_h(const int* __restrict__ hidx,
                                                float* __restrict__ h){
  int i = blockIdx.x*256 + threadIdx.x;
  int hv = *hidx;
  if (i < NN*DD) h[i] = ((i >> 5) == hv) ? 0.f : 100.f;
}

// t[n] = dot(h[n], rel_layer5) for msg_score
__global__ __launch_bounds__(256) void k_dot(const float* __restrict__ h,
                                             const float* __restrict__ rel6,
                                             float* __restrict__ tdot){
  int n0 = blockIdx.x*256 + threadIdx.x;
  int n = (n0 < NN) ? n0 : NN-1;
  const float* relr = rel6 + 5*32;
  float s = 0.f;
  #pragma unroll
  for (int d = 0; d < 32; ++d) s += h[n*32 + d] * relr[d];
  if (n0 < NN) tdot[n0] = s;
}

// ---------------- fused per-layer kernel ----------------
// Block = 64 nodes, 512 threads = 8 waves. Phase 1 = R13's proven unroll-4
// (issue 4 independent h dwordx4 + 4 csr prefetches, one wait per batch --
// R14's explicit 2-stage pipeline regressed: rotation + VGPR cost beat the
// latency saved; compiler already clumps the 4 gathers). CSR is now
// fixed-stride buckets: s0 = n*64, deg = cursor[n] (row_start array gone;
// bucket tails zeroed so unconditional prologue/prefetch reads are safe).
// Phase 2: packed fp32 j-split, wave-uniform W -> s_load; x comes from the
// lane's OWN h row via 8 dwordx4 (hT array deleted -> no hT_next store).
template<bool PRED>
__global__ __launch_bounds__(512, 6) void k_layer(const float* __restrict__ h,
                                               const float* __restrict__ rel6,
                                               const int* __restrict__ cursor,
                                               const int2* __restrict__ csr,
                                               const int* __restrict__ hidx,
                                               const float* __restrict__ tdot,
                                               const float* __restrict__ lin_W,
                                               const float* __restrict__ lin_b,
                                               const float* __restrict__ scale_arr,
                                               const float* __restrict__ inv_arr,
                                               float* __restrict__ h_next,
                                               float* __restrict__ pred_out,
                                               int l){
  __shared__ float sh[128*65];
  int tid = threadIdx.x;
  int base = blockIdx.x * 64;
  int hv0 = *hidx;

  // ---- phase 1: aggregation (one 8-lane group per node, unroll-4) ----
  {
    int nl   = tid >> 3;     // group = node index in block, 0..63
    int quad = tid & 7;      // dims quad*4..+3
    float4 r4 = ((const float4*)(rel6 + l*32))[quad];
    int n0 = base + nl;
    bool valid = n0 < NN;
    int n = valid ? n0 : NN-1;
    int deg = cursor[n];
    int s0 = n*BSTR, s1 = s0 + deg;
    float S10=0.f,S11=0.f,S12=0.f,S13=0.f;
    float S20=0.f,S21=0.f,S22=0.f,S23=0.f;
    float M0=-INFINITY,M1=-INFINITY,M2=-INFINITY,M3=-INFINITY;
    float m0=INFINITY,m1=INFINITY,m2=INFINITY,m3=INFINITY;
    float best=-INFINITY; int bi=NN;

#define ACC1(C, A, T) { \
    float w = __int_as_float(C.y); \
    float p0=w*A.x, p1=w*A.y, p2=w*A.z, p3=w*A.w; \
    S10+=p0; S11+=p1; S12+=p2; S13+=p3; \
    S20+=p0*A.x; S21+=p1*A.y; S22+=p2*A.z; S23+=p3*A.w; \
    M0=fmaxf(M0,p0); M1=fmaxf(M1,p1); M2=fmaxf(M2,p2); M3=fmaxf(M3,p3); \
    m0=fminf(m0,p0); m1=fminf(m1,p1); m2=fminf(m2,p2); m3=fminf(m3,p3); \
    if (PRED){ \
      float sv = w*T; \
      if (sv > best){ best = sv; bi = C.x; } \
      else if (sv == best && C.x < bi) bi = C.x; \
    } }

    // prologue reads are unconditional: bucket tail entries are zeroed
    int2 cA = csr[s0],   cB = csr[s0+1], cC = csr[s0+2], cD = csr[s0+3];
    int e = s0;
    for (; e + 4 <= s1; e += 4){
      float4 a  = ((const float4*)(h + cA.x*32))[quad];
      float4 b  = ((const float4*)(h + cB.x*32))[quad];
      float4 c4 = ((const float4*)(h + cC.x*32))[quad];
      float4 d4 = ((const float4*)(h + cD.x*32))[quad];
      float tA=0.f, tB=0.f, tC=0.f, tD=0.f;
      if (PRED){ tA = tdot[cA.x]; tB = tdot[cB.x]; tC = tdot[cC.x]; tD = tdot[cD.x]; }
      int2 nA = csr[e+4], nB = csr[e+5], nC = csr[e+6], nD = csr[e+7];
      ACC1(cA, a, tA)
      ACC1(cB, b, tB)
      ACC1(cC, c4, tC)
      ACC1(cD, d4, tD)
      cA = nA; cB = nB; cC = nC; cD = nD;
    }
    // tail 0..3 edges (cA..cC hold csr[e..e+2])
    if (e < s1){
      float4 a = ((const float4*)(h + cA.x*32))[quad];
      float tA = 0.f; if (PRED) tA = tdot[cA.x];
      ACC1(cA, a, tA)
      if (e + 1 < s1){
        float4 b = ((const float4*)(h + cB.x*32))[quad];
        float tB = 0.f; if (PRED) tB = tdot[cB.x];
        ACC1(cB, b, tB)
        if (e + 2 < s1){
          float4 c4 = ((const float4*)(h + cC.x*32))[quad];
          float tC = 0.f; if (PRED) tC = tdot[cC.x];
          ACC1(cC, c4, tC)
        }
      }
    }
#undef ACC1

    // finalize (no cross-lane reduction needed)
    float bnd = (n == hv0) ? 0.f : 100.f;
    float cntf = (float)(deg + 1);
#define FIN(cc, rc, S1c, S2c, Mc, mc) { \
    float mxv, mnv; \
    if (deg > 0){ \
      float em = (rc >= 0.f) ? rc*Mc : rc*mc; \
      float en = (rc >= 0.f) ? rc*mc : rc*Mc; \
      mxv = fmaxf(em, bnd); mnv = fminf(en, bnd); \
    } else { mxv = bnd; mnv = bnd; } \
    float meanv = (rc*S1c + bnd) / cntf; \
    float sq    = (rc*rc*S2c + bnd*bnd) / cntf; \
    float sdv   = sqrtf(fmaxf(sq - meanv*meanv, 1e-6f)); \
    int d = quad*4 + cc; \
    sh[(d*4+0)*65 + nl] = meanv; \
    sh[(d*4+1)*65 + nl] = mxv; \
    sh[(d*4+2)*65 + nl] = mnv; \
    sh[(d*4+3)*65 + nl] = sdv; }
    FIN(0, r4.x, S10, S20, M0, m0)
    FIN(1, r4.y, S11, S21, M1, m1)
    FIN(2, r4.z, S12, S22, M2, m2)
    FIN(3, r4.w, S13, S23, M3, m3)
#undef FIN
    if (PRED && valid && quad == 0){
      float ss = (n == hv0) ? 0.f : 3200.f;   // boundary self-loop row sum, w=1
      if (ss > best){ best = ss; bi = n; }
      else if (ss == best && n < bi) bi = n;
      pred_out[n] = (float)bi;
    }
  }
  __syncthreads();

  // ---- phase 2: linear (8 waves, wave w -> j0 = w*4; node = lane) ----
  // packed fp32 (v_pk_fma_f32); x from own h row (8 dwordx4, one wait)
  {
    const float* Wl = lin_W + (size_t)l * 13312;   // 416*32
    int lane = tid & 63;
    int j0 = __builtin_amdgcn_readfirstlane((tid >> 6) * 4);  // 0,4,...,28
    int n0 = base + lane;
    int n = (n0 < NN) ? n0 : NN-1;
    float sc = scale_arr[n], iv = inv_arr[n];
    const float4* hr = (const float4*)(h + (size_t)n*32);
    float4 x0=hr[0],x1=hr[1],x2=hr[2],x3=hr[3],x4=hr[4],x5=hr[5],x6=hr[6],x7=hr[7];
    v2f a01, a23;
    a01[0] = lin_b[l*32 + j0 + 0]; a01[1] = lin_b[l*32 + j0 + 1];
    a23[0] = lin_b[l*32 + j0 + 2]; a23[1] = lin_b[l*32 + j0 + 3];

#define KONE(XV, K) { \
    v2f xv2; xv2[0] = XV; xv2[1] = XV; \
    const v2f* wr2 = (const v2f*)(Wl + (K)*32 + j0); \
    a01 += xv2 * wr2[0]; \
    a23 += xv2 * wr2[1]; }
#define KQ(X, KB) KONE(X.x, KB+0) KONE(X.y, KB+1) KONE(X.z, KB+2) KONE(X.w, KB+3)
    KQ(x0, 0) KQ(x1, 4) KQ(x2, 8) KQ(x3, 12)
    KQ(x4, 16) KQ(x5, 20) KQ(x6, 24) KQ(x7, 28)
#undef KQ
#undef KONE

    for (int kp = 0; kp < 128; ++kp){
      float f = sh[kp*65 + lane];
      int d = kp >> 2, c = kp & 3;
      const v2f* w2 = (const v2f*)(Wl + (32 + d*12 + c*3)*32 + j0);
      float f1 = f*sc, f2 = f*iv;
      v2f fv;  fv[0]=f;  fv[1]=f;
      v2f f1v; f1v[0]=f1; f1v[1]=f1;
      v2f f2v; f2v[0]=f2; f2v[1]=f2;
      // rows are 32 floats = 16 v2f apart
      a01 += fv*w2[0] + f1v*w2[16] + f2v*w2[32];
      a23 += fv*w2[1] + f1v*w2[17] + f2v*w2[33];
    }

    if (n0 < NN){
      float vs[4] = { a01[0], a01[1], a23[0], a23[1] };
      #pragma unroll
      for (int j = 0; j < 4; ++j)
        h_next[n0*32 + j0 + j] = fmaxf(vs[j], 0.f);
    }
  }
}

// ---------------- final MLP (reads h row-major) ----------------
__global__ __launch_bounds__(256) void k_mlp(const float* __restrict__ h,
                                             const float* __restrict__ qc,
                                             const float* __restrict__ W1,
                                             const float* __restrict__ W2,
                                             const float* __restrict__ b2,
                                             float* __restrict__ out_score){
  int n0 = blockIdx.x*256 + threadIdx.x;
  int n = (n0 < NN) ? n0 : NN-1;
  float xr[32];
  const float4* hr = (const float4*)(h + (size_t)n*32);
  #pragma unroll
  for (int q = 0; q < 8; ++q){
    float4 x = hr[q];
    xr[q*4+0]=x.x; xr[q*4+1]=x.y; xr[q*4+2]=x.z; xr[q*4+3]=x.w;
  }
  float acc[64];
  #pragma unroll
  for (int j = 0; j < 64; ++j) acc[j] = qc[j];
  #pragma unroll
  for (int k = 0; k < 32; ++k){
    float xv = xr[k];
    const float* wr = W1 + k*64;
    #pragma unroll
    for (int j = 0; j < 64; ++j) acc[j] += xv * wr[j];
  }
  float s = b2[0];
  #pragma unroll
  for (int j = 0; j < 64; ++j) s += fmaxf(acc[j], 0.f) * W2[j];
  if (n0 < NN) out_score[n0] = s;
}

// ---------------- host launch ----------------
extern "C" void kernel_launch(void* const* d_in, const int* in_sizes, int n_in,
                              void* d_out, int out_size, void* d_ws, size_t ws_size,
                              hipStream_t stream){
  const int*   node_in  = (const int*)d_in[0];
  const int*   node_out = (const int*)d_in[1];
  const float* ew       = (const float*)d_in[2];
  const int*   hidx     = (const int*)d_in[3];
  const float* qw       = (const float*)d_in[4];
  const float* rel_W    = (const float*)d_in[5];
  const float* rel_b    = (const float*)d_in[6];
  const float* lin_W    = (const float*)d_in[7];
  const float* lin_b    = (const float*)d_in[8];
  const float* W1       = (const float*)d_in[9];
  const float* b1       = (const float*)d_in[10];
  const float* W2       = (const float*)d_in[11];
  const float* b2       = (const float*)d_in[12];
  float* out_score = (float*)d_out;
  float* out_pred  = out_score + NN;

  char* w = (char*)d_ws;
  size_t off = 0;
  auto take = [&](size_t bytes)->char*{
    char* p = w + off;
    off = (off + bytes + 255) & ~(size_t)255;
    return p;
  };
  // contiguous zero block: buckets | cursor | deg_w | logsum
  size_t bucket_elems = (size_t)NN * BSTR;            // int2 entries
  char*  zb       = take(bucket_elems*8 + (size_t)NN*4 + (size_t)NN*4 + 256);
  int2*  csr      = (int2*)zb;
  int*   cursor   = (int*)(zb + bucket_elems*8);
  float* deg_w    = (float*)(cursor + NN);
  float* logsum   = (float*)(deg_w + NN);
  int zc = (int)(bucket_elems*2 + NN + NN + 64);

  float* rel6      = (float*)take(192*4);
  float* qc        = (float*)take(64*4);
  float* scale_arr = (float*)take((size_t)NN*4);
  float* inv_arr   = (float*)take((size_t)NN*4);
  float* tdot      = (float*)take((size_t)NN*4);
  float* h_a       = (float*)take((size_t)NN*32*4);
  float* h_b       = (float*)take((size_t)NN*32*4);

  int nb  = (NN + 255) / 256;   // 196
  int nlb = (NN + 63) / 64;     // 782
  k_zero   <<<(zc+255)/256, 256, 0, stream>>>((float*)zb, zc);
  k_fillcsr<<<(EE+255)/256, 256, 0, stream>>>(node_in, node_out, ew, cursor, csr);
  k_sumw   <<<nb, 256, 0, stream>>>(csr, cursor, deg_w, logsum);
  k_scales <<<nb, 256, 0, stream>>>(deg_w, logsum, scale_arr, inv_arr);
  k_prep   <<<1, 256, 0, stream>>>(qw, rel_W, rel_b, W1, b1, rel6, qc);
  k_init_h <<<(NN*DD+255)/256, 256, 0, stream>>>(hidx, h_a);

  float* hc = h_a;
  float* hn = h_b;
  for (int l = 0; l < 6; ++l){
    if (l == 5){
      k_dot<<<nb, 256, 0, stream>>>(hc, rel6, tdot);
      k_layer<true><<<nlb, 512, 0, stream>>>(hc, rel6, cursor, csr, hidx, tdot,
                                             lin_W, lin_b, scale_arr, inv_arr,
                                             hn, out_pred, l);
    } else {
      k_layer<false><<<nlb, 512, 0, stream>>>(hc, rel6, cursor, csr, hidx, tdot,
                                              lin_W, lin_b, scale_arr, inv_arr,
                                              hn, out_pred, l);
    }
    float* t1 = hc; hc = hn; hn = t1;
  }
  k_mlp<<<nb, 256, 0, stream>>>(hc, qc, W1, W2, b2, out_score);
}

// Round 16
// 465.172 us; speedup vs baseline: 1.2089x; 1.0541x over previous
//
#include <hip/hip_runtime.h>
#include <math.h>

#define NN 50000
#define EE 800000
#define DD 32
#define BSTR 64    // bucket stride (max degree ~45 at Poisson(16); +8 pad fits)
#define NPART 8    // node-range partitions, mapped to XCDs via blockIdx&7
#define CPB 128    // edge chunks per partition (grid = 8*128 = 1024 blocks)

typedef float v2f __attribute__((ext_vector_type(2)));

// ---------------- setup kernels ----------------

__global__ __launch_bounds__(256) void k_zero(float* p, int count){
  int i = blockIdx.x*256 + threadIdx.x;
  if (i < count) p[i] = 0.f;
}

// XCD-partitioned one-pass CSR build. Block b owns node range (b&7)*6250..+6250
// (blockIdx%8 -> XCD round-robin is a locality heuristic only) and scans edge
// chunk b>>3. Each bucket slice + its cursors are then written by one XCD ->
// lines stay in that L2 until one write-back (R15: 51 MB write-amp from
// cross-XCD scatter). node_out is read 8x (L3-resident).
__global__ __launch_bounds__(256) void k_fillcsr(const int* __restrict__ node_in,
                                                 const int* __restrict__ node_out,
                                                 const float* __restrict__ ew,
                                                 int* __restrict__ cursor,
                                                 int2* __restrict__ csr){
  int part  = blockIdx.x & (NPART-1);
  int group = blockIdx.x >> 3;
  const int per = (EE + CPB - 1) / CPB;   // 6250
  int e0 = group * per;
  int e1 = (e0 + per < EE) ? (e0 + per) : EE;
  unsigned lo = (unsigned)part * 6250u;
  unsigned hi = lo + 6250u;
  for (int e = e0 + threadIdx.x; e < e1; e += 256){
    unsigned o = (unsigned)node_out[e];
    if (o >= lo && o < hi){
      int pos = atomicAdd(&cursor[o], 1);
      int2 v; v.x = node_in[e]; v.y = __float_as_int(ew[e]);
      csr[o*BSTR + pos] = v;
    }
  }
}

// per-node sum(w) over its bucket row + global logsum reduce + zero the
// 8-entry pad tail (all k_layer's unconditional reads land in [0, deg+8)).
__global__ __launch_bounds__(256) void k_sumw(int2* __restrict__ csr,
                                              const int* __restrict__ cursor,
                                              float* __restrict__ deg_w,
                                              float* __restrict__ logsum){
  __shared__ float sf[256];
  int t = threadIdx.x; int n = blockIdx.x*256 + t;
  float s = 0.f;
  if (n < NN){
    int deg = cursor[n];
    int2* row = csr + n*BSTR;
    for (int i = 0; i < deg; ++i) s += __int_as_float(row[i].y);
    deg_w[n] = s;
    #pragma unroll
    for (int i = 0; i < 8; ++i) row[deg + i] = make_int2(0, 0);
  }
  sf[t] = (n < NN) ? logf(s + 1.f) : 0.f;
  __syncthreads();
  for (int off = 128; off > 0; off >>= 1){
    if (t < off) sf[t] += sf[t+off];
    __syncthreads();
  }
  if (t == 0) atomicAdd(logsum, sf[0]);
}

__global__ __launch_bounds__(256) void k_scales(const float* __restrict__ deg_w,
                                                const float* __restrict__ logsum,
                                                float* __restrict__ scale_arr,
                                                float* __restrict__ inv_arr){
  int n = blockIdx.x*256 + threadIdx.x;
  if (n < NN){
    float mean = *logsum / (float)NN;
    float s = logf(deg_w[n] + 1.f) / mean;
    scale_arr[n] = s;
    inv_arr[n]   = 1.f / fmaxf(s, 0.01f);
  }
}

// rel_input per layer (6x32) and query-part of final MLP (64)
__global__ __launch_bounds__(256) void k_prep(const float* __restrict__ qw,
                                              const float* __restrict__ rel_W,
                                              const float* __restrict__ rel_b,
                                              const float* __restrict__ W1,
                                              const float* __restrict__ b1,
                                              float* __restrict__ rel6,
                                              float* __restrict__ qc){
  int t = threadIdx.x;
  if (t < 192){
    int l = t >> 5, j = t & 31;
    float s = rel_b[t];
    for (int d = 0; d < 32; ++d) s += qw[d] * rel_W[l*1024 + d*32 + j];
    rel6[t] = s;
  } else if (t < 256){
    int j = t - 192;
    float s = b1[j];
    for (int k = 0; k < 32; ++k) s += qw[k] * W1[(32+k)*64 + j];
    qc[j] = s;
  }
}

__global__ __launch_bounds__(256) void k_init_h(const int* __restrict__ hidx,
                                                float* __restrict__ h){
  int i = blockIdx.x*256 + threadIdx.x;
  int hv = *hidx;
  if (i < NN*DD) h[i] = ((i >> 5) == hv) ? 0.f : 100.f;
}

// t[n] = dot(h[n], rel_layer5) for msg_score
__global__ __launch_bounds__(256) void k_dot(const float* __restrict__ h,
                                             const float* __restrict__ rel6,
                                             float* __restrict__ tdot){
  int n0 = blockIdx.x*256 + threadIdx.x;
  int n = (n0 < NN) ? n0 : NN-1;
  const float* relr = rel6 + 5*32;
  float s = 0.f;
  #pragma unroll
  for (int d = 0; d < 32; ++d) s += h[n*32 + d] * relr[d];
  if (n0 < NN) tdot[n0] = s;
}

// ---------------- fused per-layer kernel ----------------
// Block = 64 nodes, 512 threads = 8 waves. Phase 1 = R13's proven unroll-4
// (issue 4 independent h dwordx4 + 4 csr prefetches, one wait per batch).
// CSR is fixed-stride buckets: s0 = n*64, deg = cursor[n]; tail entries
// [deg, deg+8) zeroed by k_sumw so unconditional reads are safe.
// Phase 2: packed fp32 j-split, wave-uniform W -> s_load; x from the lane's
// own h row via 8 dwordx4.
template<bool PRED>
__global__ __launch_bounds__(512, 6) void k_layer(const float* __restrict__ h,
                                               const float* __restrict__ rel6,
                                               const int* __restrict__ cursor,
                                               const int2* __restrict__ csr,
                                               const int* __restrict__ hidx,
                                               const float* __restrict__ tdot,
                                               const float* __restrict__ lin_W,
                                               const float* __restrict__ lin_b,
                                               const float* __restrict__ scale_arr,
                                               const float* __restrict__ inv_arr,
                                               float* __restrict__ h_next,
                                               float* __restrict__ pred_out,
                                               int l){
  __shared__ float sh[128*65];
  int tid = threadIdx.x;
  int base = blockIdx.x * 64;
  int hv0 = *hidx;

  // ---- phase 1: aggregation (one 8-lane group per node, unroll-4) ----
  {
    int nl   = tid >> 3;     // group = node index in block, 0..63
    int quad = tid & 7;      // dims quad*4..+3
    float4 r4 = ((const float4*)(rel6 + l*32))[quad];
    int n0 = base + nl;
    bool valid = n0 < NN;
    int n = valid ? n0 : NN-1;
    int deg = cursor[n];
    int s0 = n*BSTR, s1 = s0 + deg;
    float S10=0.f,S11=0.f,S12=0.f,S13=0.f;
    float S20=0.f,S21=0.f,S22=0.f,S23=0.f;
    float M0=-INFINITY,M1=-INFINITY,M2=-INFINITY,M3=-INFINITY;
    float m0=INFINITY,m1=INFINITY,m2=INFINITY,m3=INFINITY;
    float best=-INFINITY; int bi=NN;

#define ACC1(C, A, T) { \
    float w = __int_as_float(C.y); \
    float p0=w*A.x, p1=w*A.y, p2=w*A.z, p3=w*A.w; \
    S10+=p0; S11+=p1; S12+=p2; S13+=p3; \
    S20+=p0*A.x; S21+=p1*A.y; S22+=p2*A.z; S23+=p3*A.w; \
    M0=fmaxf(M0,p0); M1=fmaxf(M1,p1); M2=fmaxf(M2,p2); M3=fmaxf(M3,p3); \
    m0=fminf(m0,p0); m1=fminf(m1,p1); m2=fminf(m2,p2); m3=fminf(m3,p3); \
    if (PRED){ \
      float sv = w*T; \
      if (sv > best){ best = sv; bi = C.x; } \
      else if (sv == best && C.x < bi) bi = C.x; \
    } }

    // prologue reads are unconditional: pad tail [deg, deg+8) is zeroed
    int2 cA = csr[s0],   cB = csr[s0+1], cC = csr[s0+2], cD = csr[s0+3];
    int e = s0;
    for (; e + 4 <= s1; e += 4){
      float4 a  = ((const float4*)(h + cA.x*32))[quad];
      float4 b  = ((const float4*)(h + cB.x*32))[quad];
      float4 c4 = ((const float4*)(h + cC.x*32))[quad];
      float4 d4 = ((const float4*)(h + cD.x*32))[quad];
      float tA=0.f, tB=0.f, tC=0.f, tD=0.f;
      if (PRED){ tA = tdot[cA.x]; tB = tdot[cB.x]; tC = tdot[cC.x]; tD = tdot[cD.x]; }
      int2 nA = csr[e+4], nB = csr[e+5], nC = csr[e+6], nD = csr[e+7];
      ACC1(cA, a, tA)
      ACC1(cB, b, tB)
      ACC1(cC, c4, tC)
      ACC1(cD, d4, tD)
      cA = nA; cB = nB; cC = nC; cD = nD;
    }
    // tail 0..3 edges (cA..cC hold csr[e..e+2])
    if (e < s1){
      float4 a = ((const float4*)(h + cA.x*32))[quad];
      float tA = 0.f; if (PRED) tA = tdot[cA.x];
      ACC1(cA, a, tA)
      if (e + 1 < s1){
        float4 b = ((const float4*)(h + cB.x*32))[quad];
        float tB = 0.f; if (PRED) tB = tdot[cB.x];
        ACC1(cB, b, tB)
        if (e + 2 < s1){
          float4 c4 = ((const float4*)(h + cC.x*32))[quad];
          float tC = 0.f; if (PRED) tC = tdot[cC.x];
          ACC1(cC, c4, tC)
        }
      }
    }
#undef ACC1

    // finalize (no cross-lane reduction needed)
    float bnd = (n == hv0) ? 0.f : 100.f;
    float cntf = (float)(deg + 1);
#define FIN(cc, rc, S1c, S2c, Mc, mc) { \
    float mxv, mnv; \
    if (deg > 0){ \
      float em = (rc >= 0.f) ? rc*Mc : rc*mc; \
      float en = (rc >= 0.f) ? rc*mc : rc*Mc; \
      mxv = fmaxf(em, bnd); mnv = fminf(en, bnd); \
    } else { mxv = bnd; mnv = bnd; } \
    float meanv = (rc*S1c + bnd) / cntf; \
    float sq    = (rc*rc*S2c + bnd*bnd) / cntf; \
    float sdv   = sqrtf(fmaxf(sq - meanv*meanv, 1e-6f)); \
    int d = quad*4 + cc; \
    sh[(d*4+0)*65 + nl] = meanv; \
    sh[(d*4+1)*65 + nl] = mxv; \
    sh[(d*4+2)*65 + nl] = mnv; \
    sh[(d*4+3)*65 + nl] = sdv; }
    FIN(0, r4.x, S10, S20, M0, m0)
    FIN(1, r4.y, S11, S21, M1, m1)
    FIN(2, r4.z, S12, S22, M2, m2)
    FIN(3, r4.w, S13, S23, M3, m3)
#undef FIN
    if (PRED && valid && quad == 0){
      float ss = (n == hv0) ? 0.f : 3200.f;   // boundary self-loop row sum, w=1
      if (ss > best){ best = ss; bi = n; }
      else if (ss == best && n < bi) bi = n;
      pred_out[n] = (float)bi;
    }
  }
  __syncthreads();

  // ---- phase 2: linear (8 waves, wave w -> j0 = w*4; node = lane) ----
  // packed fp32 (v_pk_fma_f32); x from own h row (8 dwordx4, one wait)
  {
    const float* Wl = lin_W + (size_t)l * 13312;   // 416*32
    int lane = tid & 63;
    int j0 = __builtin_amdgcn_readfirstlane((tid >> 6) * 4);  // 0,4,...,28
    int n0 = base + lane;
    int n = (n0 < NN) ? n0 : NN-1;
    float sc = scale_arr[n], iv = inv_arr[n];
    const float4* hr = (const float4*)(h + (size_t)n*32);
    float4 x0=hr[0],x1=hr[1],x2=hr[2],x3=hr[3],x4=hr[4],x5=hr[5],x6=hr[6],x7=hr[7];
    v2f a01, a23;
    a01[0] = lin_b[l*32 + j0 + 0]; a01[1] = lin_b[l*32 + j0 + 1];
    a23[0] = lin_b[l*32 + j0 + 2]; a23[1] = lin_b[l*32 + j0 + 3];

#define KONE(XV, K) { \
    v2f xv2; xv2[0] = XV; xv2[1] = XV; \
    const v2f* wr2 = (const v2f*)(Wl + (K)*32 + j0); \
    a01 += xv2 * wr2[0]; \
    a23 += xv2 * wr2[1]; }
#define KQ(X, KB) KONE(X.x, KB+0) KONE(X.y, KB+1) KONE(X.z, KB+2) KONE(X.w, KB+3)
    KQ(x0, 0) KQ(x1, 4) KQ(x2, 8) KQ(x3, 12)
    KQ(x4, 16) KQ(x5, 20) KQ(x6, 24) KQ(x7, 28)
#undef KQ
#undef KONE

    for (int kp = 0; kp < 128; ++kp){
      float f = sh[kp*65 + lane];
      int d = kp >> 2, c = kp & 3;
      const v2f* w2 = (const v2f*)(Wl + (32 + d*12 + c*3)*32 + j0);
      float f1 = f*sc, f2 = f*iv;
      v2f fv;  fv[0]=f;  fv[1]=f;
      v2f f1v; f1v[0]=f1; f1v[1]=f1;
      v2f f2v; f2v[0]=f2; f2v[1]=f2;
      // rows are 32 floats = 16 v2f apart
      a01 += fv*w2[0] + f1v*w2[16] + f2v*w2[32];
      a23 += fv*w2[1] + f1v*w2[17] + f2v*w2[33];
    }

    if (n0 < NN){
      float vs[4] = { a01[0], a01[1], a23[0], a23[1] };
      #pragma unroll
      for (int j = 0; j < 4; ++j)
        h_next[n0*32 + j0 + j] = fmaxf(vs[j], 0.f);
    }
  }
}

// ---------------- final MLP (reads h row-major) ----------------
__global__ __launch_bounds__(256) void k_mlp(const float* __restrict__ h,
                                             const float* __restrict__ qc,
                                             const float* __restrict__ W1,
                                             const float* __restrict__ W2,
                                             const float* __restrict__ b2,
                                             float* __restrict__ out_score){
  int n0 = blockIdx.x*256 + threadIdx.x;
  int n = (n0 < NN) ? n0 : NN-1;
  float xr[32];
  const float4* hr = (const float4*)(h + (size_t)n*32);
  #pragma unroll
  for (int q = 0; q < 8; ++q){
    float4 x = hr[q];
    xr[q*4+0]=x.x; xr[q*4+1]=x.y; xr[q*4+2]=x.z; xr[q*4+3]=x.w;
  }
  float acc[64];
  #pragma unroll
  for (int j = 0; j < 64; ++j) acc[j] = qc[j];
  #pragma unroll
  for (int k = 0; k < 32; ++k){
    float xv = xr[k];
    const float* wr = W1 + k*64;
    #pragma unroll
    for (int j = 0; j < 64; ++j) acc[j] += xv * wr[j];
  }
  float s = b2[0];
  #pragma unroll
  for (int j = 0; j < 64; ++j) s += fmaxf(acc[j], 0.f) * W2[j];
  if (n0 < NN) out_score[n0] = s;
}

// ---------------- host launch ----------------
extern "C" void kernel_launch(void* const* d_in, const int* in_sizes, int n_in,
                              void* d_out, int out_size, void* d_ws, size_t ws_size,
                              hipStream_t stream){
  const int*   node_in  = (const int*)d_in[0];
  const int*   node_out = (const int*)d_in[1];
  const float* ew       = (const float*)d_in[2];
  const int*   hidx     = (const int*)d_in[3];
  const float* qw       = (const float*)d_in[4];
  const float* rel_W    = (const float*)d_in[5];
  const float* rel_b    = (const float*)d_in[6];
  const float* lin_W    = (const float*)d_in[7];
  const float* lin_b    = (const float*)d_in[8];
  const float* W1       = (const float*)d_in[9];
  const float* b1       = (const float*)d_in[10];
  const float* W2       = (const float*)d_in[11];
  const float* b2       = (const float*)d_in[12];
  float* out_score = (float*)d_out;
  float* out_pred  = out_score + NN;

  char* w = (char*)d_ws;
  size_t off = 0;
  auto take = [&](size_t bytes)->char*{
    char* p = w + off;
    off = (off + bytes + 255) & ~(size_t)255;
    return p;
  };
  size_t bucket_elems = (size_t)NN * BSTR;            // int2 entries
  int2*  csr      = (int2*)take(bucket_elems*8);
  // contiguous zero block: cursor | deg_w | logsum
  char*  zb       = take((size_t)NN*4 + (size_t)NN*4 + 256);
  int*   cursor   = (int*)zb;
  float* deg_w    = (float*)(cursor + NN);
  float* logsum   = (float*)(deg_w + NN);
  int zc = NN + NN + 64;

  float* rel6      = (float*)take(192*4);
  float* qc        = (float*)take(64*4);
  float* scale_arr = (float*)take((size_t)NN*4);
  float* inv_arr   = (float*)take((size_t)NN*4);
  float* tdot      = (float*)take((size_t)NN*4);
  float* h_a       = (float*)take((size_t)NN*32*4);
  float* h_b       = (float*)take((size_t)NN*32*4);

  int nb  = (NN + 255) / 256;   // 196
  int nlb = (NN + 63) / 64;     // 782
  k_zero   <<<(zc+255)/256, 256, 0, stream>>>((float*)zb, zc);
  k_fillcsr<<<NPART*CPB, 256, 0, stream>>>(node_in, node_out, ew, cursor, csr);
  k_sumw   <<<nb, 256, 0, stream>>>(csr, cursor, deg_w, logsum);
  k_scales <<<nb, 256, 0, stream>>>(deg_w, logsum, scale_arr, inv_arr);
  k_prep   <<<1, 256, 0, stream>>>(qw, rel_W, rel_b, W1, b1, rel6, qc);
  k_init_h <<<(NN*DD+255)/256, 256, 0, stream>>>(hidx, h_a);

  float* hc = h_a;
  float* hn = h_b;
  for (int l = 0; l < 6; ++l){
    if (l == 5){
      k_dot<<<nb, 256, 0, stream>>>(hc, rel6, tdot);
      k_layer<true><<<nlb, 512, 0, stream>>>(hc, rel6, cursor, csr, hidx, tdot,
                                             lin_W, lin_b, scale_arr, inv_arr,
                                             hn, out_pred, l);
    } else {
      k_layer<false><<<nlb, 512, 0, stream>>>(hc, rel6, cursor, csr, hidx, tdot,
                                              lin_W, lin_b, scale_arr, inv_arr,
                                              hn, out_pred, l);
    }
    float* t1 = hc; hc = hn; hn = t1;
  }
  k_mlp<<<nb, 256, 0, stream>>>(hc, qc, W1, W2, b2, out_score);
}